// Round 5
// baseline (995.625 us; speedup 1.0000x reference)
//
#include <hip/hip_runtime.h>

typedef __attribute__((ext_vector_type(8))) short short8;
typedef __attribute__((ext_vector_type(4))) float floatx4;

#define B_ 2
#define S_ 2048
#define E_ 2048
#define H_ 16
#define D_ 128

#define NEG_S  (-3.0e4f)
#define LOG2E  1.4426950408889634f

__device__ inline float bf2f(unsigned short u) {
    union { unsigned int i; float f; } v; v.i = ((unsigned int)u) << 16; return v.f;
}
__device__ inline unsigned short f2bf(float f) {
    union { float f; unsigned int i; } v; v.f = f;
    unsigned int r = v.i + 0x7FFFu + ((v.i >> 16) & 1u);
    return (unsigned short)(r >> 16);
}

// Precompute RoPE cos/sin tables: [S][D/2] fp32. 1 MB total.
__global__ void rope_tab(float* __restrict__ cosT, float* __restrict__ sinT) {
    int idx = blockIdx.x * 256 + threadIdx.x;   // 2048*64 entries
    int s = idx >> 6, j = idx & 63;
    float inv = exp2f(-(float)(2 * j) * (13.287712379549449f / 128.0f));
    float ang = (float)s * inv;
    cosT[idx] = cosf(ang);
    sinT[idx] = sinf(ang);
}

// C = A @ W^T. A: (rows,2048) fp32 (aBf16=0) or bf16 (aBf16=1), row-major.
// W: (2048,2048) fp32 row-major. bf16 MFMA, fp32 accum.
// dstMode 0: fp32 dst[m*2048+n], m local to grid.
// dstMode 1: fp32 head-layout dst[((b*16+h)*2048+s)*128+d], m global 0..4095.
// dstMode 3: bf16 dst[m*2048+n], m global (flat (B,S,E) bf16 - q intermediate).
__global__ __launch_bounds__(256) void gemm_bt(const void* __restrict__ A,
                                               const float* __restrict__ Bw,
                                               void* __restrict__ dst,
                                               int aBf16, int dstMode) {
    __shared__ __align__(16) unsigned short As[64][40];
    __shared__ __align__(16) unsigned short Bs[64][40];
    int t = threadIdx.x;
    int wave = t >> 6, lane = t & 63;
    int quad = lane >> 4, l16 = lane & 15;
    floatx4 acc[4];
#pragma unroll
    for (int i = 0; i < 4; i++) acc[i] = (floatx4)(0.f);

    int r = t >> 2, kc = (t & 3) * 8;
    int ra = blockIdx.x * 64 + r;
    int rb = blockIdx.y * 64 + r;

    for (int k0 = 0; k0 < E_; k0 += 32) {
        if (aBf16) {
            const unsigned short* Ab = (const unsigned short*)A + (size_t)ra * E_ + kc + k0;
            *(uint4*)&As[r][kc] = *(const uint4*)Ab;
        } else {
            const float* Af = (const float*)A + (size_t)ra * E_ + kc + k0;
            float4 f0 = *(const float4*)Af;
            float4 f1 = *(const float4*)(Af + 4);
            unsigned short u[8] = {f2bf(f0.x), f2bf(f0.y), f2bf(f0.z), f2bf(f0.w),
                                   f2bf(f1.x), f2bf(f1.y), f2bf(f1.z), f2bf(f1.w)};
            *(uint4*)&As[r][kc] = *(uint4*)u;
        }
        {
            const float* Bf = Bw + (size_t)rb * E_ + kc + k0;
            float4 g0 = *(const float4*)Bf;
            float4 g1 = *(const float4*)(Bf + 4);
            unsigned short u[8] = {f2bf(g0.x), f2bf(g0.y), f2bf(g0.z), f2bf(g0.w),
                                   f2bf(g1.x), f2bf(g1.y), f2bf(g1.z), f2bf(g1.w)};
            *(uint4*)&Bs[r][kc] = *(uint4*)u;
        }
        __syncthreads();
        short8 a = *(const short8*)&As[wave * 16 + l16][quad * 8];
#pragma unroll
        for (int ct = 0; ct < 4; ct++) {
            short8 bfr = *(const short8*)&Bs[ct * 16 + l16][quad * 8];
            acc[ct] = __builtin_amdgcn_mfma_f32_16x16x32_bf16(a, bfr, acc[ct], 0, 0, 0);
        }
        __syncthreads();
    }
#pragma unroll
    for (int ct = 0; ct < 4; ct++) {
#pragma unroll
        for (int rr = 0; rr < 4; rr++) {
            int m = blockIdx.x * 64 + wave * 16 + quad * 4 + rr;
            int n = blockIdx.y * 64 + ct * 16 + l16;
            float val = acc[ct][rr];
            if (dstMode == 0) {
                ((float*)dst)[(size_t)m * E_ + n] = val;
            } else if (dstMode == 1) {
                int b = m >> 11, s = m & 2047, h = n >> 7, d = n & 127;
                ((float*)dst)[(((size_t)(b * H_ + h)) * S_ + s) * D_ + d] = val;
            } else {
                ((unsigned short*)dst)[(size_t)m * E_ + n] = f2bf(val);
            }
        }
    }
}

// Flash-style causal attention, one batch, one qtile-chunk.
// Grid: (R/64 qtiles, 16 heads). Q: bf16 flat (S,E) slice for this batch,
// un-roped. K,V: fp32 (H,S,D) this batch, un-roped. RoPE on load via tables.
// Output: midChunk bf16 (R, E), rows relative to qtile0*64.
__global__ __launch_bounds__(256) void attn_fwd(const unsigned short* __restrict__ Qf,
                                                const float* __restrict__ Kb0,
                                                const float* __restrict__ Vb0,
                                                const float* __restrict__ cosT,
                                                const float* __restrict__ sinT,
                                                unsigned short* __restrict__ Omid,
                                                int qtile0) {
    __shared__ __align__(16) unsigned short Ks[64][136];
    __shared__ __align__(16) unsigned short Vt[128][72];
    __shared__ __align__(16) unsigned short Ps[4][16][72];

    int t = threadIdx.x;
    int wave = t >> 6, lane = t & 63;
    int quad = lane >> 4, l16 = lane & 15;
    int qtile = qtile0 + blockIdx.x, h = blockIdx.y;
    const float* Kb = Kb0 + (size_t)h * S_ * D_;
    const float* Vb = Vb0 + (size_t)h * S_ * D_;

    // Q fragments (A-operand: row=lane&15, k=quad*8+j), roped in-register.
    int sq = qtile * 64 + wave * 16 + l16;
    short8 qf[4];
#pragma unroll
    for (int ks = 0; ks < 4; ks++) {
        int d0 = ks * 32 + quad * 8;
        union { uint4 u4; unsigned short u[8]; } un;
        un.u4 = *(const uint4*)&Qf[(size_t)sq * E_ + h * D_ + d0];
#pragma unroll
        for (int i = 0; i < 4; i++) {
            int j = (d0 >> 1) + i;
            float c = cosT[sq * 64 + j], s = sinT[sq * 64 + j];
            float x1 = bf2f(un.u[2 * i]), x2 = bf2f(un.u[2 * i + 1]);
            un.u[2 * i] = f2bf(x1 * c - x2 * s);
            un.u[2 * i + 1] = f2bf(x1 * s + x2 * c);
        }
        qf[ks] = *(short8*)un.u;
    }

    floatx4 O[8];
#pragma unroll
    for (int i = 0; i < 8; i++) O[i] = (floatx4)(0.f);
    float mrow[4], lrow[4];
#pragma unroll
    for (int r = 0; r < 4; r++) { mrow[r] = NEG_S; lrow[r] = 0.f; }

    const float scale = 0.08838834764831845f; // 1/sqrt(128)

    for (int kt = 0; kt <= qtile; kt++) {
        __syncthreads();
        // Stage K (fp32 -> rope -> bf16) and V (fp32 -> bf16, transposed).
        int r = t >> 2;
#pragma unroll
        for (int it = 0; it < 4; it++) {
            int d0 = (t & 3) * 8 + it * 32;
            int sk = kt * 64 + r;
            float4 ka = *(const float4*)&Kb[(size_t)sk * D_ + d0];
            float4 kb2 = *(const float4*)&Kb[(size_t)sk * D_ + d0 + 4];
            float xs[8] = {ka.x, ka.y, ka.z, ka.w, kb2.x, kb2.y, kb2.z, kb2.w};
            unsigned short u[8];
#pragma unroll
            for (int i = 0; i < 4; i++) {
                int j = (d0 >> 1) + i;
                float c = cosT[sk * 64 + j], s = sinT[sk * 64 + j];
                float x1 = xs[2 * i], x2 = xs[2 * i + 1];
                u[2 * i]     = f2bf(x1 * c - x2 * s);
                u[2 * i + 1] = f2bf(x1 * s + x2 * c);
            }
            *(uint4*)&Ks[r][d0] = *(uint4*)u;
            float4 va = *(const float4*)&Vb[(size_t)sk * D_ + d0];
            float4 vb2 = *(const float4*)&Vb[(size_t)sk * D_ + d0 + 4];
            float vs[8] = {va.x, va.y, va.z, va.w, vb2.x, vb2.y, vb2.z, vb2.w};
#pragma unroll
            for (int i = 0; i < 8; i++) Vt[d0 + i][r] = f2bf(vs[i]);
        }
        __syncthreads();

        // S = Q K^T (per wave: 16 rows x 64 cols)
        floatx4 sc[4];
#pragma unroll
        for (int ct = 0; ct < 4; ct++) sc[ct] = (floatx4)(0.f);
#pragma unroll
        for (int ks = 0; ks < 4; ks++) {
#pragma unroll
            for (int ct = 0; ct < 4; ct++) {
                short8 kf = *(const short8*)&Ks[ct * 16 + l16][ks * 32 + quad * 8];
                sc[ct] = __builtin_amdgcn_mfma_f32_16x16x32_bf16(qf[ks], kf, sc[ct], 0, 0, 0);
            }
        }
        // scale + causal mask (finite sentinel)
        int rowbase = qtile * 64 + wave * 16 + quad * 4;
#pragma unroll
        for (int ct = 0; ct < 4; ct++) {
            int col = kt * 64 + ct * 16 + l16;
#pragma unroll
            for (int rr = 0; rr < 4; rr++) {
                float x = sc[ct][rr] * scale;
                sc[ct][rr] = (col > rowbase + rr) ? NEG_S : x;
            }
        }
        // online softmax (row reductions across 16 lanes of each quad)
        float alpha[4];
#pragma unroll
        for (int rr = 0; rr < 4; rr++) {
            float mx = fmaxf(fmaxf(sc[0][rr], sc[1][rr]), fmaxf(sc[2][rr], sc[3][rr]));
            mx = fmaxf(mx, __shfl_xor(mx, 1));
            mx = fmaxf(mx, __shfl_xor(mx, 2));
            mx = fmaxf(mx, __shfl_xor(mx, 4));
            mx = fmaxf(mx, __shfl_xor(mx, 8));
            float mnew = fmaxf(mrow[rr], mx);
            alpha[rr] = exp2f((mrow[rr] - mnew) * LOG2E);
            mrow[rr] = mnew;
        }
#pragma unroll
        for (int rr = 0; rr < 4; rr++) {
            float ps = 0.f;
#pragma unroll
            for (int ct = 0; ct < 4; ct++) {
                float p = exp2f((sc[ct][rr] - mrow[rr]) * LOG2E);
                sc[ct][rr] = p;
                ps += p;
            }
            ps += __shfl_xor(ps, 1);
            ps += __shfl_xor(ps, 2);
            ps += __shfl_xor(ps, 4);
            ps += __shfl_xor(ps, 8);
            lrow[rr] = lrow[rr] * alpha[rr] + ps;
        }
#pragma unroll
        for (int c8 = 0; c8 < 8; c8++)
#pragma unroll
            for (int rr = 0; rr < 4; rr++) O[c8][rr] *= alpha[rr];

        // P: C-layout -> LDS -> A-layout
#pragma unroll
        for (int ct = 0; ct < 4; ct++)
#pragma unroll
            for (int rr = 0; rr < 4; rr++)
                Ps[wave][quad * 4 + rr][ct * 16 + l16] = f2bf(sc[ct][rr]);
        __syncthreads();

        // O += P V
#pragma unroll
        for (int ka2 = 0; ka2 < 2; ka2++) {
            short8 pa = *(const short8*)&Ps[wave][l16][ka2 * 32 + quad * 8];
#pragma unroll
            for (int c8 = 0; c8 < 8; c8++) {
                short8 vf = *(const short8*)&Vt[c8 * 16 + l16][ka2 * 32 + quad * 8];
                O[c8] = __builtin_amdgcn_mfma_f32_16x16x32_bf16(pa, vf, O[c8], 0, 0, 0);
            }
        }
    }

    // normalize + store bf16 to mid chunk (rows relative to qtile0*64)
#pragma unroll
    for (int rr = 0; rr < 4; rr++) {
        float inv = 1.f / lrow[rr];
        int lrw = blockIdx.x * 64 + wave * 16 + quad * 4 + rr;
#pragma unroll
        for (int c8 = 0; c8 < 8; c8++) {
            int d = c8 * 16 + l16;
            Omid[(size_t)lrw * E_ + h * D_ + d] = f2bf(O[c8][rr] * inv);
        }
    }
}

extern "C" void kernel_launch(void* const* d_in, const int* in_sizes, int n_in,
                              void* d_out, int out_size, void* d_ws, size_t ws_size,
                              hipStream_t stream) {
    const float* x  = (const float*)d_in[0];
    const float* Wq = (const float*)d_in[1];
    const float* Wk = (const float*)d_in[2];
    const float* Wv = (const float*)d_in[3];
    const float* Wo = (const float*)d_in[4];

    float* out_attn = (float*)d_out;                              // (B,S,E) fp32
    float* out_k = out_attn + (size_t)B_ * H_ * S_ * D_;          // (B,H,S,D) fp32 pre-rope
    float* out_v = out_k + (size_t)B_ * H_ * S_ * D_;             // (B,H,S,D) fp32

    // q intermediate: bf16, flat (B,S,E), in the BACK half of the attn_out
    // region: bytes [16.8MB, 33.5MB) of d_out. Write-frontier proof vs the
    // interleaved Wo writes: Wo b0 writes [0,16.8M) only; for b1, after chunk
    // c the Wo frontier is 16.8M+8cR KB <= q1 read start 25.2M+4cR KB since
    // 4cR KB <= 8.4MB (cR <= 2048-R).
    unsigned short* q_tmp = (unsigned short*)(out_attn + (size_t)S_ * E_);

    // ws: [cosT 512K | sinT 512K | mid chunk R*2048 bf16], capped at ws_size.
    char* ws = (char*)d_ws;
    float* cosT = (float*)ws;
    float* sinT = cosT + S_ * (D_ / 2);
    size_t tab_bytes = 2u * S_ * (D_ / 2) * sizeof(float);        // 1 MB
    unsigned short* mid = (unsigned short*)(ws + tab_bytes);
    size_t avail = ws_size > tab_bytes ? ws_size - tab_bytes : 0;
    int R = 64;
    for (int r = 2048; r >= 64; r >>= 1) {
        if ((size_t)r * E_ * 2 <= avail) { R = r; break; }
    }

    hipLaunchKernelGGL(rope_tab, dim3(512), dim3(256), 0, stream, cosT, sinT);
    dim3 gg(64, 32);
    hipLaunchKernelGGL(gemm_bt, gg, dim3(256), 0, stream, (const void*)x, Wq, (void*)q_tmp, 0, 3);
    hipLaunchKernelGGL(gemm_bt, gg, dim3(256), 0, stream, (const void*)x, Wk, (void*)out_k, 0, 1);
    hipLaunchKernelGGL(gemm_bt, gg, dim3(256), 0, stream, (const void*)x, Wv, (void*)out_v, 0, 1);

    const size_t bhsd = (size_t)H_ * S_ * D_;   // per-batch elems in (B,H,S,D)
    for (int b = 0; b < B_; b++) {
        const unsigned short* qb = q_tmp + (size_t)b * S_ * E_;
        for (int c = 0; c < S_ / 64; c += R / 64) {
            // attention for q-rows [c*64, c*64 + R) of batch b -> mid chunk
            hipLaunchKernelGGL(attn_fwd, dim3(R / 64, H_), dim3(256), 0, stream,
                               qb, out_k + b * bhsd, out_v + b * bhsd,
                               cosT, sinT, mid, c);
            // project those rows: out_attn[b, c*64 ...] = mid @ Wo^T
            hipLaunchKernelGGL(gemm_bt, dim3(R / 64, 32), dim3(256), 0, stream,
                               (const void*)mid, Wo,
                               (void*)(out_attn + ((size_t)b * S_ + c * 64) * E_), 1, 0);
        }
    }
}